// Round 1
// baseline (40862.473 us; speedup 1.0000x reference)
//
#include <hip/hip_runtime.h>
#include <math.h>

#define HD 512
#define NB 32
#define LS 2048

// ---------------------------------------------------------------------------
// Kernel 1: Xi = x @ Wi0 + bi0  (M=B*L=65536, N=K=512), written into d_out's
// [B,L,H] region. Xi[b][t] is read at step t and only overwritten (by h1[t])
// at step t+1, so reuse of d_out as the Xi buffer is race-free.
// ---------------------------------------------------------------------------
__global__ __launch_bounds__(256) void xi_gemm(const float* __restrict__ x,
                                               const float* __restrict__ Wi0,
                                               const float* __restrict__ bi0,
                                               float* __restrict__ out) {
  __shared__ float As[16][68];  // [k][m], padded
  __shared__ float Bs[16][68];  // [k][n], padded
  const int bn = blockIdx.x * 64;   // n block (8 total)  -> W tile stays in L2
  const int bm = blockIdx.y * 64;   // m block (1024 total)
  const int tid = threadIdx.x;
  const int tm = (tid & 15) * 4;
  const int tn = (tid >> 4) * 4;
  float acc[4][4] = {};
  for (int k0 = 0; k0 < HD; k0 += 16) {
    {
      const int r = tid >> 2, ks = (tid & 3) * 4;
      const float4 av = *(const float4*)(x + (size_t)(bm + r) * HD + k0 + ks);
      As[ks + 0][r] = av.x; As[ks + 1][r] = av.y;
      As[ks + 2][r] = av.z; As[ks + 3][r] = av.w;
      const int kk = tid >> 4, ns = (tid & 15) * 4;
      *(float4*)&Bs[kk][ns] = *(const float4*)(Wi0 + (size_t)(k0 + kk) * HD + bn + ns);
    }
    __syncthreads();
#pragma unroll
    for (int k = 0; k < 16; ++k) {
      const float4 a = *(const float4*)&As[k][tm];
      const float4 b = *(const float4*)&Bs[k][tn];
      acc[0][0] = fmaf(a.x, b.x, acc[0][0]); acc[0][1] = fmaf(a.x, b.y, acc[0][1]);
      acc[0][2] = fmaf(a.x, b.z, acc[0][2]); acc[0][3] = fmaf(a.x, b.w, acc[0][3]);
      acc[1][0] = fmaf(a.y, b.x, acc[1][0]); acc[1][1] = fmaf(a.y, b.y, acc[1][1]);
      acc[1][2] = fmaf(a.y, b.z, acc[1][2]); acc[1][3] = fmaf(a.y, b.w, acc[1][3]);
      acc[2][0] = fmaf(a.z, b.x, acc[2][0]); acc[2][1] = fmaf(a.z, b.y, acc[2][1]);
      acc[2][2] = fmaf(a.z, b.z, acc[2][2]); acc[2][3] = fmaf(a.z, b.w, acc[2][3]);
      acc[3][0] = fmaf(a.w, b.x, acc[3][0]); acc[3][1] = fmaf(a.w, b.y, acc[3][1]);
      acc[3][2] = fmaf(a.w, b.z, acc[3][2]); acc[3][3] = fmaf(a.w, b.w, acc[3][3]);
    }
    __syncthreads();
  }
  const float4 bias = *(const float4*)(bi0 + bn + tn);
#pragma unroll
  for (int i = 0; i < 4; ++i) {
    float4 v;
    v.x = acc[i][0] + bias.x; v.y = acc[i][1] + bias.y;
    v.z = acc[i][2] + bias.z; v.w = acc[i][3] + bias.w;
    *(float4*)(out + (size_t)(bm + tm + i) * HD + bn + tn) = v;
  }
}

// ---------------------------------------------------------------------------
// Kernel 2: transpose the 3 recurrent weight matrices into ws so step-kernel
// threads can read their column with float4 loads. WT[z][c][k] = W_z[k][c].
// grid (2, 512, 3), 256 thr.
// ---------------------------------------------------------------------------
__global__ void transpose_w(const float* __restrict__ Wh0,
                            const float* __restrict__ Wi1,
                            const float* __restrict__ Wh1,
                            float* __restrict__ WT) {
  const int k = blockIdx.y;
  const int c = (blockIdx.x << 8) + threadIdx.x;
  const int z = blockIdx.z;
  const float* src = (z == 0) ? Wh0 : (z == 1) ? Wi1 : Wh1;
  WT[(size_t)z * HD * HD + (size_t)c * HD + k] = src[(size_t)k * HD + c];
}

// ---------------------------------------------------------------------------
// Kernel 3: init hidden-state double buffers from h0 input.
// hbuf layout (floats): [0,32768) h0 dbuf (parity*16384), [32768,65536) h1 dbuf.
// h[-1] lives at parity 1 ((-1)&1 == 1). grid 128, 256 thr.
// ---------------------------------------------------------------------------
__global__ void init_h(const float* __restrict__ h0, float* __restrict__ hbuf) {
  const int i = blockIdx.x * 256 + threadIdx.x;  // [0, 2*16384)
  const float v = h0[i];
  if (i < 16384) hbuf[16384 + i] = v;                  // layer 0, parity 1
  else           hbuf[32768 + 16384 + (i - 16384)] = v; // layer 1, parity 1
}

// ---------------------------------------------------------------------------
// Kernel 4: one pipelined RNN step. Launch t (t in [0, LS]):
//   blocks   0..127: h0[t]   = tanh(Xi[t] + h0[t-1] @ Wh0 + bh0)      (t < LS)
//   blocks 128..255: h1[t-1] = tanh(h0[t-1] @ Wi1 + bi1
//                                   + h1[t-2] @ Wh1 + bh1)            (t >= 1)
// Kernel boundaries provide the cross-step / cross-XCD ordering.
// Block = 16 cols x 8 batches x 2 k-halves; per-thread 256/512 fp32 MACs via
// float4 loads of transposed weight columns (L2-hot) + h vectors.
// ---------------------------------------------------------------------------
__global__ __launch_bounds__(256) void rnn_step(const float* __restrict__ WT,
                                                const float* __restrict__ bh0,
                                                const float* __restrict__ bi1,
                                                const float* __restrict__ bh1,
                                                const float* __restrict__ Xi,
                                                float* __restrict__ out,
                                                float* __restrict__ hbuf,
                                                const int t) {
  __shared__ float red[256];
  const int tid = threadIdx.x;
  const int bid = blockIdx.x;
  const int c  = tid & 15;
  const int bs = (tid >> 4) & 7;
  const int kh = tid >> 7;
  float* h0b = hbuf;
  float* h1b = hbuf + 32768;
  const size_t OUT0 = (size_t)NB * LS * HD;

  if (bid < 128) {                       // ---- layer 0, step t ----
    if (t >= LS) return;
    const int cg = bid & 31, bg = bid >> 5;
    const int col = cg * 16 + c;
    const int b = bg * 8 + bs;
    const float4* hp = (const float4*)(h0b + ((t + 1) & 1) * 16384 + b * HD) + kh * 64;
    const float4* wp = (const float4*)(WT + (size_t)col * HD) + kh * 64;
    float acc = 0.f;
#pragma unroll 8
    for (int j = 0; j < 64; ++j) {
      const float4 h4 = hp[j], w4 = wp[j];
      acc = fmaf(h4.x, w4.x, acc); acc = fmaf(h4.y, w4.y, acc);
      acc = fmaf(h4.z, w4.z, acc); acc = fmaf(h4.w, w4.w, acc);
    }
    red[tid] = acc;
    __syncthreads();
    if (tid < 128) {                     // kh==0 threads finish each output
      float s = red[tid] + red[tid + 128]
              + Xi[((size_t)b * LS + t) * HD + col] + bh0[col];
      const float hv = tanhf(s);
      h0b[(t & 1) * 16384 + b * HD + col] = hv;
      if (t == LS - 1) out[OUT0 + b * HD + col] = hv;   // h_final layer 0
    }
  } else {                               // ---- layer 1, step t-1 ----
    const int tt = t - 1;
    if (tt < 0) return;
    const int cg = (bid - 128) & 31, bg = (bid - 128) >> 5;
    const int col = cg * 16 + c;
    const int b = bg * 8 + bs;
    const float4* h0p = (const float4*)(h0b + (tt & 1) * 16384 + b * HD) + kh * 64;
    const float4* h1p = (const float4*)(h1b + ((tt + 1) & 1) * 16384 + b * HD) + kh * 64;
    const float4* wip = (const float4*)(WT + (size_t)HD * HD + (size_t)col * HD) + kh * 64;
    const float4* whp = (const float4*)(WT + 2 * (size_t)HD * HD + (size_t)col * HD) + kh * 64;
    float acc = 0.f;
#pragma unroll 4
    for (int j = 0; j < 64; ++j) {
      const float4 a4 = h0p[j], wi4 = wip[j];
      acc = fmaf(a4.x, wi4.x, acc); acc = fmaf(a4.y, wi4.y, acc);
      acc = fmaf(a4.z, wi4.z, acc); acc = fmaf(a4.w, wi4.w, acc);
      const float4 b4 = h1p[j], wh4 = whp[j];
      acc = fmaf(b4.x, wh4.x, acc); acc = fmaf(b4.y, wh4.y, acc);
      acc = fmaf(b4.z, wh4.z, acc); acc = fmaf(b4.w, wh4.w, acc);
    }
    red[tid] = acc;
    __syncthreads();
    if (tid < 128) {
      float s = red[tid] + red[tid + 128] + bi1[col] + bh1[col];
      const float hv = tanhf(s);
      h1b[(tt & 1) * 16384 + b * HD + col] = hv;
      out[((size_t)b * LS + tt) * HD + col] = hv;       // sequence output
      if (tt == LS - 1) out[OUT0 + NB * HD + b * HD + col] = hv;  // h_final L1
    }
  }
}

// ---------------------------------------------------------------------------
// ws usage (floats): [0,65536) hidden-state double buffers,
//                    [65536, 65536+3*512*512) transposed weights (3.25 MB total).
// ---------------------------------------------------------------------------
extern "C" void kernel_launch(void* const* d_in, const int* in_sizes, int n_in,
                              void* d_out, int out_size, void* d_ws, size_t ws_size,
                              hipStream_t stream) {
  const float* x  = (const float*)d_in[0];
  const float* h0 = (const float*)d_in[1];
  const float* Wi = (const float*)d_in[2];
  const float* bi = (const float*)d_in[3];
  const float* Wh = (const float*)d_in[4];
  const float* bh = (const float*)d_in[5];
  float* out = (float*)d_out;
  float* ws  = (float*)d_ws;

  const float* Wi0 = Wi;
  const float* Wi1 = Wi + (size_t)HD * HD;
  const float* bi0 = bi;
  const float* bi1 = bi + HD;
  const float* Wh0 = Wh;
  const float* Wh1 = Wh + (size_t)HD * HD;
  const float* bh0 = bh;
  const float* bh1 = bh + HD;

  float* WT = ws + 65536;

  xi_gemm<<<dim3(8, 1024), 256, 0, stream>>>(x, Wi0, bi0, out);
  transpose_w<<<dim3(2, 512, 3), 256, 0, stream>>>(Wh0, Wi1, Wh1, WT);
  init_h<<<128, 256, 0, stream>>>(h0, ws);

  for (int t = 0; t <= LS; ++t) {
    rnn_step<<<256, 256, 0, stream>>>(WT, bh0, bi1, bh1, out, out, ws, t);
  }
}

// Round 2
// 37217.899 us; speedup vs baseline: 1.0979x; 1.0979x over previous
//
#include <hip/hip_runtime.h>
#include <math.h>

#define HD 512
#define NB 32
#define LS 2048
#define GBLK 128u                       // blocks per barrier group (64 L0 + 64 L1)
#define SYNC_OFF (65536 + 3 * HD * HD)  // float offset of sync area in ws

// ---------------------------------------------------------------------------
// Kernel 1 (unchanged, known-good): Xi = x @ Wi0 + bi0 into d_out's [B,L,H].
// Xi[b][t] is read at persistent-iter t; h1[t] overwrites it at iter t+1.
// ---------------------------------------------------------------------------
__global__ __launch_bounds__(256) void xi_gemm(const float* __restrict__ x,
                                               const float* __restrict__ Wi0,
                                               const float* __restrict__ bi0,
                                               float* __restrict__ out) {
  __shared__ float As[16][68];
  __shared__ float Bs[16][68];
  const int bn = blockIdx.x * 64;
  const int bm = blockIdx.y * 64;
  const int tid = threadIdx.x;
  const int tm = (tid & 15) * 4;
  const int tn = (tid >> 4) * 4;
  float acc[4][4] = {};
  for (int k0 = 0; k0 < HD; k0 += 16) {
    {
      const int r = tid >> 2, ks = (tid & 3) * 4;
      const float4 av = *(const float4*)(x + (size_t)(bm + r) * HD + k0 + ks);
      As[ks + 0][r] = av.x; As[ks + 1][r] = av.y;
      As[ks + 2][r] = av.z; As[ks + 3][r] = av.w;
      const int kk = tid >> 4, ns = (tid & 15) * 4;
      *(float4*)&Bs[kk][ns] = *(const float4*)(Wi0 + (size_t)(k0 + kk) * HD + bn + ns);
    }
    __syncthreads();
#pragma unroll
    for (int k = 0; k < 16; ++k) {
      const float4 a = *(const float4*)&As[k][tm];
      const float4 b = *(const float4*)&Bs[k][tn];
      acc[0][0] = fmaf(a.x, b.x, acc[0][0]); acc[0][1] = fmaf(a.x, b.y, acc[0][1]);
      acc[0][2] = fmaf(a.x, b.z, acc[0][2]); acc[0][3] = fmaf(a.x, b.w, acc[0][3]);
      acc[1][0] = fmaf(a.y, b.x, acc[1][0]); acc[1][1] = fmaf(a.y, b.y, acc[1][1]);
      acc[1][2] = fmaf(a.y, b.z, acc[1][2]); acc[1][3] = fmaf(a.y, b.w, acc[1][3]);
      acc[2][0] = fmaf(a.z, b.x, acc[2][0]); acc[2][1] = fmaf(a.z, b.y, acc[2][1]);
      acc[2][2] = fmaf(a.z, b.z, acc[2][2]); acc[2][3] = fmaf(a.z, b.w, acc[2][3]);
      acc[3][0] = fmaf(a.w, b.x, acc[3][0]); acc[3][1] = fmaf(a.w, b.y, acc[3][1]);
      acc[3][2] = fmaf(a.w, b.z, acc[3][2]); acc[3][3] = fmaf(a.w, b.w, acc[3][3]);
    }
    __syncthreads();
  }
  const float4 bias = *(const float4*)(bi0 + bn + tn);
#pragma unroll
  for (int i = 0; i < 4; ++i) {
    float4 v;
    v.x = acc[i][0] + bias.x; v.y = acc[i][1] + bias.y;
    v.z = acc[i][2] + bias.z; v.w = acc[i][3] + bias.w;
    *(float4*)(out + (size_t)(bm + tm + i) * HD + bn + tn) = v;
  }
}

// ---------------------------------------------------------------------------
// Kernel 2 (unchanged): WT[z][c][k] = W_z[k][c], z in {Wh0, Wi1, Wh1}.
// ---------------------------------------------------------------------------
__global__ void transpose_w(const float* __restrict__ Wh0,
                            const float* __restrict__ Wi1,
                            const float* __restrict__ Wh1,
                            float* __restrict__ WT) {
  const int k = blockIdx.y;
  const int c = (blockIdx.x << 8) + threadIdx.x;
  const int z = blockIdx.z;
  const float* src = (z == 0) ? Wh0 : (z == 1) ? Wi1 : Wh1;
  WT[(size_t)z * HD * HD + (size_t)c * HD + k] = src[(size_t)k * HD + c];
}

// ---------------------------------------------------------------------------
// Kernel 3: init hidden double-buffers (parity 1 = h[-1]) + zero sync counters.
// ---------------------------------------------------------------------------
__global__ void init_h(const float* __restrict__ h0, float* __restrict__ ws) {
  const int i = blockIdx.x * 256 + threadIdx.x;  // [0, 32768)
  const float v = h0[i];
  if (i < 16384) ws[16384 + i] = v;                   // layer 0, parity 1
  else           ws[32768 + 16384 + (i - 16384)] = v; // layer 1, parity 1
  if (blockIdx.x == 0) {
    unsigned* syncp = (unsigned*)(ws + SYNC_OFF);
    syncp[threadIdx.x] = 0;                           // cnt/flag for both groups
  }
}

// ---------------------------------------------------------------------------
// Persistent recurrence kernel helpers
// ---------------------------------------------------------------------------
__device__ __forceinline__ float dot4(float4 a, float4 b, float acc) {
  acc = fmaf(a.x, b.x, acc); acc = fmaf(a.y, b.y, acc);
  acc = fmaf(a.z, b.z, acc); acc = fmaf(a.w, b.w, acc);
  return acc;
}

// Monotone-epoch group barrier. Release/acquire at agent scope gives
// cross-XCD visibility for the h writes that precede it (G16).
__device__ __forceinline__ void group_barrier(unsigned* cnt, unsigned* flag,
                                              unsigned target) {
  __syncthreads();  // per-wave s_waitcnt drains this block's h stores to L2
  if (threadIdx.x == 0) {
    unsigned prev = __hip_atomic_fetch_add(cnt, 1u, __ATOMIC_ACQ_REL,
                                           __HIP_MEMORY_SCOPE_AGENT);
    if (prev == target - 1u) {
      __hip_atomic_store(flag, target, __ATOMIC_RELEASE, __HIP_MEMORY_SCOPE_AGENT);
    } else {
      while (__hip_atomic_load(flag, __ATOMIC_ACQUIRE, __HIP_MEMORY_SCOPE_AGENT)
             < target) {
        __builtin_amdgcn_s_sleep(2);
      }
    }
  }
  __syncthreads();
}

// ---------------------------------------------------------------------------
// Kernel 4: persistent pipelined recurrence. 256 blocks x 256 threads
// (cooperative). bid: g = bid&1 (batch group of 16), layer = (bid>>1)&1,
// cb = bid>>2 -> 8 cols. Iter t: L0 computes h0[t] (t<LS), L1 computes h1[t-1]
// (t>=1); one 128-block group barrier per iter. Weights live in VGPRs
// (128 floats/thread, loaded once). h broadcast via ws double buffers in L2.
// ---------------------------------------------------------------------------
__global__ __launch_bounds__(256, 1) void rnn_persist(
    const float* __restrict__ WT,
    const float* __restrict__ bh0,
    const float* __restrict__ bi1,
    const float* __restrict__ bh1,
    float* __restrict__ outbuf,   // d_out: Xi source + seq out + h_final
    float* __restrict__ ws) {
  __shared__ float part[128 * 36];

  const int tid = threadIdx.x;
  const int bid = blockIdx.x;
  const int g = bid & 1;
  const int layer = (bid >> 1) & 1;
  const int cb = bid >> 2;          // [0,64)
  const int col0 = cb * 8;
  const int bbase = g * 16;

  float* h0b = ws;
  float* h1b = ws + 32768;
  unsigned* syncp = (unsigned*)(ws + SYNC_OFF);
  unsigned* cnt_g = syncp + g * 64;
  unsigned* flag_g = syncp + g * 64 + 32;
  const size_t OUT0 = (size_t)NB * LS * HD;

  // finisher decode (threads 0..127 finalize one (col,b) output each)
  const int fco = tid & 7;
  const int fbo = tid >> 3;         // [0,16)
  const int fcol = col0 + fco;
  const int fb = bbase + fbo;

  if (layer == 0) {
    const int cg = tid & 1;                 // 2 col-groups of 4
    const int ks = (tid >> 1) & 15;         // 16 k-slices of 32
    const int kb = ks * 32;
    const int bg = tid >> 5;                // 8 b-groups of 2
    // permanent weights: 4 cols x 32 k of Wh0^T
    float4 w[4][8];
#pragma unroll
    for (int ci = 0; ci < 4; ++ci)
#pragma unroll
      for (int kk = 0; kk < 8; ++kk)
        w[ci][kk] = *(const float4*)(WT + (size_t)(col0 + cg * 4 + ci) * HD + kb + kk * 4);
    float fbias = 0.f;
    if (tid < 128) fbias = bh0[fcol];

    for (int t = 0; t <= LS; ++t) {
      if (t < LS) {
        float xi = 0.f;
        if (tid < 128) xi = outbuf[((size_t)fb * LS + t) * HD + fcol];
        const float* hs = h0b + ((t + 1) & 1) * 16384 + (size_t)(bbase + bg * 2) * HD + kb;
        float4 ha[8], hb4[8];
#pragma unroll
        for (int j = 0; j < 8; ++j) {
          ha[j] = ((const float4*)hs)[j];
          hb4[j] = ((const float4*)(hs + HD))[j];
        }
        float acc[4][2] = {};
#pragma unroll
        for (int kk = 0; kk < 8; ++kk)
#pragma unroll
          for (int ci = 0; ci < 4; ++ci) {
            acc[ci][0] = dot4(w[ci][kk], ha[kk], acc[ci][0]);
            acc[ci][1] = dot4(w[ci][kk], hb4[kk], acc[ci][1]);
          }
#pragma unroll
        for (int ci = 0; ci < 4; ++ci)
#pragma unroll
          for (int bj = 0; bj < 2; ++bj)
            part[((bg * 2 + bj) * 8 + cg * 4 + ci) * 36 + ks] = acc[ci][bj];
        __syncthreads();
        if (tid < 128) {
          const float4* pp = (const float4*)&part[tid * 36];
          const float4 p0 = pp[0], p1 = pp[1], p2 = pp[2], p3 = pp[3];
          float s = (((p0.x + p0.y) + (p0.z + p0.w)) + ((p1.x + p1.y) + (p1.z + p1.w)))
                  + (((p2.x + p2.y) + (p2.z + p2.w)) + ((p3.x + p3.y) + (p3.z + p3.w)))
                  + xi + fbias;
          const float hv = tanhf(s);
          h0b[(t & 1) * 16384 + (size_t)fb * HD + fcol] = hv;
          if (t == LS - 1) outbuf[OUT0 + (size_t)fb * HD + fcol] = hv;  // h_final L0
        }
      }
      group_barrier(cnt_g, flag_g, (unsigned)(t + 1) * GBLK);
    }
  } else {
    const int m = tid >> 7;                 // matrix: 0 = Wi1 (h0), 1 = Wh1 (h1)
    const int r = tid & 127;
    const int cg = r & 1;
    const int ks = (r >> 1) & 15;
    const int kb = ks * 32;
    const int bg = r >> 5;                  // 4 b-groups of 4
    float4 w[4][8];
    const float* Wm = WT + (size_t)(1 + m) * HD * HD;
#pragma unroll
    for (int ci = 0; ci < 4; ++ci)
#pragma unroll
      for (int kk = 0; kk < 8; ++kk)
        w[ci][kk] = *(const float4*)(Wm + (size_t)(col0 + cg * 4 + ci) * HD + kb + kk * 4);
    float fbias = 0.f;
    if (tid < 128) fbias = bi1[fcol] + bh1[fcol];

    for (int t = 0; t <= LS; ++t) {
      const int tt = t - 1;
      if (tt >= 0) {
        const float* hsrc = (m == 0)
            ? h0b + (tt & 1) * 16384          // h0[tt]
            : h1b + ((tt + 1) & 1) * 16384;   // h1[tt-1]
        float acc[4][4] = {};
#pragma unroll
        for (int bj = 0; bj < 4; ++bj) {
          const float* hb = hsrc + (size_t)(bbase + bg * 4 + bj) * HD + kb;
          float4 hr[8];
#pragma unroll
          for (int j = 0; j < 8; ++j) hr[j] = ((const float4*)hb)[j];
#pragma unroll
          for (int kk = 0; kk < 8; ++kk)
#pragma unroll
            for (int ci = 0; ci < 4; ++ci)
              acc[ci][bj] = dot4(w[ci][kk], hr[kk], acc[ci][bj]);
        }
#pragma unroll
        for (int ci = 0; ci < 4; ++ci)
#pragma unroll
          for (int bj = 0; bj < 4; ++bj)
            part[((bg * 4 + bj) * 8 + cg * 4 + ci) * 36 + m * 16 + ks] = acc[ci][bj];
        __syncthreads();
        if (tid < 128) {
          const float4* pp = (const float4*)&part[tid * 36];
          float s = fbias;
#pragma unroll
          for (int j = 0; j < 8; ++j) {
            const float4 p = pp[j];
            s += ((p.x + p.y) + (p.z + p.w));
          }
          const float hv = tanhf(s);
          h1b[(tt & 1) * 16384 + (size_t)fb * HD + fcol] = hv;
          outbuf[((size_t)fb * LS + tt) * HD + fcol] = hv;
          if (tt == LS - 1) outbuf[OUT0 + NB * HD + (size_t)fb * HD + fcol] = hv;  // h_final L1
        }
      }
      group_barrier(cnt_g, flag_g, (unsigned)(t + 1) * GBLK);
    }
  }
}

// ---------------------------------------------------------------------------
// ws layout (floats): [0,65536) h dbufs; [65536, 65536+786432) WT;
// [SYNC_OFF, SYNC_OFF+256) barrier counters. ~3.25 MB (same as passing v1).
// ---------------------------------------------------------------------------
extern "C" void kernel_launch(void* const* d_in, const int* in_sizes, int n_in,
                              void* d_out, int out_size, void* d_ws, size_t ws_size,
                              hipStream_t stream) {
  const float* x  = (const float*)d_in[0];
  const float* h0 = (const float*)d_in[1];
  const float* Wi = (const float*)d_in[2];
  const float* bi = (const float*)d_in[3];
  const float* Wh = (const float*)d_in[4];
  const float* bh = (const float*)d_in[5];
  float* out = (float*)d_out;
  float* ws  = (float*)d_ws;

  const float* Wi0 = Wi;
  const float* Wi1 = Wi + (size_t)HD * HD;
  const float* bi0 = bi;
  const float* bi1 = bi + HD;
  const float* Wh0 = Wh;
  const float* Wh1 = Wh + (size_t)HD * HD;
  const float* bh0 = bh;
  const float* bh1 = bh + HD;

  const float* WT = ws + 65536;

  xi_gemm<<<dim3(8, 1024), 256, 0, stream>>>(x, Wi0, bi0, out);
  transpose_w<<<dim3(2, 512, 3), 256, 0, stream>>>(Wh0, Wi1, Wh1, ws + 65536);
  init_h<<<128, 256, 0, stream>>>(h0, ws);

  void* kargs[] = {(void*)&WT, (void*)&bh0, (void*)&bi1, (void*)&bh1,
                   (void*)&out, (void*)&ws};
  hipLaunchCooperativeKernel((const void*)rnn_persist, dim3(256), dim3(256),
                             kargs, 0, stream);
}

// Round 3
// 31694.760 us; speedup vs baseline: 1.2893x; 1.1743x over previous
//
#include <hip/hip_runtime.h>
#include <math.h>

#define HD 512
#define NB 32
#define LS 2048
#define GBLK 128u                       // blocks per barrier group (64 L0 + 64 L1)
#define SYNC_OFF (65536 + 3 * HD * HD)  // float offset of sync area in ws

typedef unsigned long long ull;

__device__ __forceinline__ float2 u2f(ull u) { return __builtin_bit_cast(float2, u); }

// ---------------------------------------------------------------------------
// Kernel 1 (unchanged, known-good): Xi = x @ Wi0 + bi0 into d_out's [B,L,H].
// ---------------------------------------------------------------------------
__global__ __launch_bounds__(256) void xi_gemm(const float* __restrict__ x,
                                               const float* __restrict__ Wi0,
                                               const float* __restrict__ bi0,
                                               float* __restrict__ out) {
  __shared__ float As[16][68];
  __shared__ float Bs[16][68];
  const int bn = blockIdx.x * 64;
  const int bm = blockIdx.y * 64;
  const int tid = threadIdx.x;
  const int tm = (tid & 15) * 4;
  const int tn = (tid >> 4) * 4;
  float acc[4][4] = {};
  for (int k0 = 0; k0 < HD; k0 += 16) {
    {
      const int r = tid >> 2, ks = (tid & 3) * 4;
      const float4 av = *(const float4*)(x + (size_t)(bm + r) * HD + k0 + ks);
      As[ks + 0][r] = av.x; As[ks + 1][r] = av.y;
      As[ks + 2][r] = av.z; As[ks + 3][r] = av.w;
      const int kk = tid >> 4, ns = (tid & 15) * 4;
      *(float4*)&Bs[kk][ns] = *(const float4*)(Wi0 + (size_t)(k0 + kk) * HD + bn + ns);
    }
    __syncthreads();
#pragma unroll
    for (int k = 0; k < 16; ++k) {
      const float4 a = *(const float4*)&As[k][tm];
      const float4 b = *(const float4*)&Bs[k][tn];
      acc[0][0] = fmaf(a.x, b.x, acc[0][0]); acc[0][1] = fmaf(a.x, b.y, acc[0][1]);
      acc[0][2] = fmaf(a.x, b.z, acc[0][2]); acc[0][3] = fmaf(a.x, b.w, acc[0][3]);
      acc[1][0] = fmaf(a.y, b.x, acc[1][0]); acc[1][1] = fmaf(a.y, b.y, acc[1][1]);
      acc[1][2] = fmaf(a.y, b.z, acc[1][2]); acc[1][3] = fmaf(a.y, b.w, acc[1][3]);
      acc[2][0] = fmaf(a.z, b.x, acc[2][0]); acc[2][1] = fmaf(a.z, b.y, acc[2][1]);
      acc[2][2] = fmaf(a.z, b.z, acc[2][2]); acc[2][3] = fmaf(a.z, b.w, acc[2][3]);
      acc[3][0] = fmaf(a.w, b.x, acc[3][0]); acc[3][1] = fmaf(a.w, b.y, acc[3][1]);
      acc[3][2] = fmaf(a.w, b.z, acc[3][2]); acc[3][3] = fmaf(a.w, b.w, acc[3][3]);
    }
    __syncthreads();
  }
  const float4 bias = *(const float4*)(bi0 + bn + tn);
#pragma unroll
  for (int i = 0; i < 4; ++i) {
    float4 v;
    v.x = acc[i][0] + bias.x; v.y = acc[i][1] + bias.y;
    v.z = acc[i][2] + bias.z; v.w = acc[i][3] + bias.w;
    *(float4*)(out + (size_t)(bm + tm + i) * HD + bn + tn) = v;
  }
}

// ---------------------------------------------------------------------------
// Kernel 2 (unchanged): WT[z][c][k] = W_z[k][c], z in {Wh0, Wi1, Wh1}.
// ---------------------------------------------------------------------------
__global__ void transpose_w(const float* __restrict__ Wh0,
                            const float* __restrict__ Wi1,
                            const float* __restrict__ Wh1,
                            float* __restrict__ WT) {
  const int k = blockIdx.y;
  const int c = (blockIdx.x << 8) + threadIdx.x;
  const int z = blockIdx.z;
  const float* src = (z == 0) ? Wh0 : (z == 1) ? Wi1 : Wh1;
  WT[(size_t)z * HD * HD + (size_t)c * HD + k] = src[(size_t)k * HD + c];
}

// ---------------------------------------------------------------------------
// Kernel 3 (unchanged): init h dbufs (parity 1 = h[-1]) + zero sync counters.
// ---------------------------------------------------------------------------
__global__ void init_h(const float* __restrict__ h0, float* __restrict__ ws) {
  const int i = blockIdx.x * 256 + threadIdx.x;  // [0, 32768)
  const float v = h0[i];
  if (i < 16384) ws[16384 + i] = v;                   // layer 0, parity 1
  else           ws[32768 + 16384 + (i - 16384)] = v; // layer 1, parity 1
  if (blockIdx.x == 0) {
    unsigned* syncp = (unsigned*)(ws + SYNC_OFF);
    syncp[threadIdx.x] = 0;
  }
}

// ---------------------------------------------------------------------------
// Group barrier, NO acquire/release fences (they lower to buffer_wbl2 /
// buffer_inv on gfx950 = full L2 flush per call — the round-2 18 us/iter bug).
// Relaxed agent atomics compile to sc1 accesses (per-access coherent at L3).
// Ordering: __syncthreads emits s_waitcnt vmcnt(0) before s_barrier, draining
// this block's coherent h stores before the arrival add is issued.
// ---------------------------------------------------------------------------
__device__ __forceinline__ void group_barrier(unsigned* cnt, unsigned target) {
  __syncthreads();
  if (threadIdx.x == 0) {
    __hip_atomic_fetch_add(cnt, 1u, __ATOMIC_RELAXED, __HIP_MEMORY_SCOPE_AGENT);
    while (__hip_atomic_load(cnt, __ATOMIC_RELAXED, __HIP_MEMORY_SCOPE_AGENT) < target)
      __builtin_amdgcn_s_sleep(1);
  }
  __syncthreads();
}

// ---------------------------------------------------------------------------
// Kernel 4: persistent pipelined recurrence (structure identical to round 2;
// only the h-dbuf accesses and barrier changed to relaxed sc1 atomics).
// Weights + Xi are plain cached loads — they now stay hot in L1/L2 because
// nothing invalidates the caches anymore.
// ---------------------------------------------------------------------------
__global__ __launch_bounds__(256, 1) void rnn_persist(
    const float* __restrict__ WT,
    const float* __restrict__ bh0,
    const float* __restrict__ bi1,
    const float* __restrict__ bh1,
    float* __restrict__ outbuf,
    float* __restrict__ ws) {
  __shared__ float part[128 * 36];

  const int tid = threadIdx.x;
  const int bid = blockIdx.x;
  const int g = bid & 1;
  const int layer = (bid >> 1) & 1;
  const int cb = bid >> 2;          // [0,64)
  const int col0 = cb * 8;
  const int bbase = g * 16;

  float* h0b = ws;
  float* h1b = ws + 32768;
  unsigned* syncp = (unsigned*)(ws + SYNC_OFF);
  unsigned* cnt_g = syncp + g * 64;
  const size_t OUT0 = (size_t)NB * LS * HD;

  const int fco = tid & 7;
  const int fbo = tid >> 3;         // [0,16)
  const int fcol = col0 + fco;
  const int fb = bbase + fbo;

  if (layer == 0) {
    const int cg = tid & 1;                 // 2 col-groups of 4
    const int ks = (tid >> 1) & 15;         // 16 k-slices of 32
    const int kb = ks * 32;
    const int bg = tid >> 5;                // 8 b-groups of 2
    float4 w[4][8];
#pragma unroll
    for (int ci = 0; ci < 4; ++ci)
#pragma unroll
      for (int kk = 0; kk < 8; ++kk)
        w[ci][kk] = *(const float4*)(WT + (size_t)(col0 + cg * 4 + ci) * HD + kb + kk * 4);
    float fbias = 0.f;
    if (tid < 128) fbias = bh0[fcol];

    for (int t = 0; t <= LS; ++t) {
      if (t < LS) {
        float xi = 0.f;
        if (tid < 128) xi = outbuf[((size_t)fb * LS + t) * HD + fcol];
        ull* hs = (ull*)(h0b + ((t + 1) & 1) * 16384 + (size_t)(bbase + bg * 2) * HD + kb);
        ull hau[16], hbu[16];
#pragma unroll
        for (int j = 0; j < 16; ++j)
          hau[j] = __hip_atomic_load(hs + j, __ATOMIC_RELAXED, __HIP_MEMORY_SCOPE_AGENT);
#pragma unroll
        for (int j = 0; j < 16; ++j)
          hbu[j] = __hip_atomic_load(hs + 256 + j, __ATOMIC_RELAXED, __HIP_MEMORY_SCOPE_AGENT);
        float acc[4][2] = {};
#pragma unroll
        for (int kk = 0; kk < 8; ++kk) {
          const float2 a0 = u2f(hau[2 * kk]), a1 = u2f(hau[2 * kk + 1]);
          const float2 b0 = u2f(hbu[2 * kk]), b1 = u2f(hbu[2 * kk + 1]);
#pragma unroll
          for (int ci = 0; ci < 4; ++ci) {
            const float4 wv = w[ci][kk];
            acc[ci][0] = fmaf(wv.x, a0.x, acc[ci][0]);
            acc[ci][0] = fmaf(wv.y, a0.y, acc[ci][0]);
            acc[ci][0] = fmaf(wv.z, a1.x, acc[ci][0]);
            acc[ci][0] = fmaf(wv.w, a1.y, acc[ci][0]);
            acc[ci][1] = fmaf(wv.x, b0.x, acc[ci][1]);
            acc[ci][1] = fmaf(wv.y, b0.y, acc[ci][1]);
            acc[ci][1] = fmaf(wv.z, b1.x, acc[ci][1]);
            acc[ci][1] = fmaf(wv.w, b1.y, acc[ci][1]);
          }
        }
#pragma unroll
        for (int ci = 0; ci < 4; ++ci)
#pragma unroll
          for (int bj = 0; bj < 2; ++bj)
            part[((bg * 2 + bj) * 8 + cg * 4 + ci) * 36 + ks] = acc[ci][bj];
        __syncthreads();
        if (tid < 128) {
          const float4* pp = (const float4*)&part[tid * 36];
          const float4 p0 = pp[0], p1 = pp[1], p2 = pp[2], p3 = pp[3];
          float s = (((p0.x + p0.y) + (p0.z + p0.w)) + ((p1.x + p1.y) + (p1.z + p1.w)))
                  + (((p2.x + p2.y) + (p2.z + p2.w)) + ((p3.x + p3.y) + (p3.z + p3.w)))
                  + xi + fbias;
          const float hv = tanhf(s);
          __hip_atomic_store((unsigned*)(h0b + (t & 1) * 16384 + (size_t)fb * HD + fcol),
                             __builtin_bit_cast(unsigned, hv),
                             __ATOMIC_RELAXED, __HIP_MEMORY_SCOPE_AGENT);
          if (t == LS - 1) outbuf[OUT0 + (size_t)fb * HD + fcol] = hv;  // h_final L0
        }
      }
      group_barrier(cnt_g, (unsigned)(t + 1) * GBLK);
    }
  } else {
    const int m = tid >> 7;                 // 0 = Wi1 (reads h0), 1 = Wh1 (reads h1)
    const int r = tid & 127;
    const int cg = r & 1;
    const int ks = (r >> 1) & 15;
    const int kb = ks * 32;
    const int bg = r >> 5;                  // 4 b-groups of 4
    float4 w[4][8];
    const float* Wm = WT + (size_t)(1 + m) * HD * HD;
#pragma unroll
    for (int ci = 0; ci < 4; ++ci)
#pragma unroll
      for (int kk = 0; kk < 8; ++kk)
        w[ci][kk] = *(const float4*)(Wm + (size_t)(col0 + cg * 4 + ci) * HD + kb + kk * 4);
    float fbias = 0.f;
    if (tid < 128) fbias = bi1[fcol] + bh1[fcol];

    for (int t = 0; t <= LS; ++t) {
      const int tt = t - 1;
      if (tt >= 0) {
        float* hsrc = (m == 0)
            ? h0b + (tt & 1) * 16384          // h0[tt]
            : h1b + ((tt + 1) & 1) * 16384;   // h1[tt-1]
        float acc[4][4] = {};
#pragma unroll
        for (int bj = 0; bj < 4; ++bj) {
          ull* hp = (ull*)(hsrc + (size_t)(bbase + bg * 4 + bj) * HD + kb);
          ull hu[16];
#pragma unroll
          for (int j = 0; j < 16; ++j)
            hu[j] = __hip_atomic_load(hp + j, __ATOMIC_RELAXED, __HIP_MEMORY_SCOPE_AGENT);
#pragma unroll
          for (int kk = 0; kk < 8; ++kk) {
            const float2 h0_ = u2f(hu[2 * kk]), h1_ = u2f(hu[2 * kk + 1]);
#pragma unroll
            for (int ci = 0; ci < 4; ++ci) {
              const float4 wv = w[ci][kk];
              acc[ci][bj] = fmaf(wv.x, h0_.x, acc[ci][bj]);
              acc[ci][bj] = fmaf(wv.y, h0_.y, acc[ci][bj]);
              acc[ci][bj] = fmaf(wv.z, h1_.x, acc[ci][bj]);
              acc[ci][bj] = fmaf(wv.w, h1_.y, acc[ci][bj]);
            }
          }
        }
#pragma unroll
        for (int ci = 0; ci < 4; ++ci)
#pragma unroll
          for (int bj = 0; bj < 4; ++bj)
            part[((bg * 4 + bj) * 8 + cg * 4 + ci) * 36 + m * 16 + ks] = acc[ci][bj];
        __syncthreads();
        if (tid < 128) {
          const float4* pp = (const float4*)&part[tid * 36];
          float s = fbias;
#pragma unroll
          for (int j = 0; j < 8; ++j) {
            const float4 p = pp[j];
            s += ((p.x + p.y) + (p.z + p.w));
          }
          const float hv = tanhf(s);
          __hip_atomic_store((unsigned*)(h1b + (tt & 1) * 16384 + (size_t)fb * HD + fcol),
                             __builtin_bit_cast(unsigned, hv),
                             __ATOMIC_RELAXED, __HIP_MEMORY_SCOPE_AGENT);
          outbuf[((size_t)fb * LS + tt) * HD + fcol] = hv;
          if (tt == LS - 1) outbuf[OUT0 + NB * HD + (size_t)fb * HD + fcol] = hv;  // h_final L1
        }
      }
      group_barrier(cnt_g, (unsigned)(t + 1) * GBLK);
    }
  }
}

// ---------------------------------------------------------------------------
// ws layout (floats): [0,65536) h dbufs; [65536,65536+786432) WT;
// [SYNC_OFF, SYNC_OFF+256) barrier counters.
// ---------------------------------------------------------------------------
extern "C" void kernel_launch(void* const* d_in, const int* in_sizes, int n_in,
                              void* d_out, int out_size, void* d_ws, size_t ws_size,
                              hipStream_t stream) {
  const float* x  = (const float*)d_in[0];
  const float* h0 = (const float*)d_in[1];
  const float* Wi = (const float*)d_in[2];
  const float* bi = (const float*)d_in[3];
  const float* Wh = (const float*)d_in[4];
  const float* bh = (const float*)d_in[5];
  float* out = (float*)d_out;
  float* ws  = (float*)d_ws;

  const float* Wi0 = Wi;
  const float* Wi1 = Wi + (size_t)HD * HD;
  const float* bi0 = bi;
  const float* bi1 = bi + HD;
  const float* Wh0 = Wh;
  const float* Wh1 = Wh + (size_t)HD * HD;
  const float* bh0 = bh;
  const float* bh1 = bh + HD;

  const float* WT = ws + 65536;

  xi_gemm<<<dim3(8, 1024), 256, 0, stream>>>(x, Wi0, bi0, out);
  transpose_w<<<dim3(2, 512, 3), 256, 0, stream>>>(Wh0, Wi1, Wh1, ws + 65536);
  init_h<<<128, 256, 0, stream>>>(h0, ws);

  void* kargs[] = {(void*)&WT, (void*)&bh0, (void*)&bi1, (void*)&bh1,
                   (void*)&out, (void*)&ws};
  hipLaunchCooperativeKernel((const void*)rnn_persist, dim3(256), dim3(256),
                             kargs, 0, stream);
}